// Round 5
// baseline (807.029 us; speedup 1.0000x reference)
//
#include <hip/hip_runtime.h>

#define NUM_USERS 200000
#define NUM_ITEMS 100000
#define N_NODES   300000
#define NNZ       4000000
#define DIM       64
#define N_ELEM   ((size_t)N_NODES * DIM)   // 19,200,000 elements

#define BKT_SHIFT 8                        // 256 rows per bucket
#define BKT_ROWS  256
#define NBKT      ((N_NODES + BKT_ROWS - 1) >> BKT_SHIFT)   // 1172
#define NSUB      8                        // per-XCD sub-frontiers per bucket
#define PAD       32                       // pad atomic counters to 128B lines

typedef unsigned int uint32;

// Native clang vector types: __builtin_nontemporal_load rejects the
// HIP_vector_type structs (round-3 lesson) but accepts these.
typedef __attribute__((ext_vector_type(4))) float         nfloat4;
typedef __attribute__((ext_vector_type(4))) int           nint4;
typedef __attribute__((ext_vector_type(2))) int           nint2;
typedef __attribute__((ext_vector_type(4))) unsigned int  nuint4;

static __device__ __forceinline__ float4 ntload(const float4* p) {
    nfloat4 v = __builtin_nontemporal_load(reinterpret_cast<const nfloat4*>(p));
    return make_float4(v.x, v.y, v.z, v.w);
}
static __device__ __forceinline__ int4 ntload(const int4* p) {
    nint4 v = __builtin_nontemporal_load(reinterpret_cast<const nint4*>(p));
    return make_int4(v.x, v.y, v.z, v.w);
}
static __device__ __forceinline__ int2 ntload(const int2* p) {
    nint2 v = __builtin_nontemporal_load(reinterpret_cast<const nint2*>(p));
    return make_int2(v.x, v.y);
}
static __device__ __forceinline__ uint4 ntload(const uint4* p) {
    nuint4 v = __builtin_nontemporal_load(reinterpret_cast<const nuint4*>(p));
    return make_uint4(v.x, v.y, v.z, v.w);
}

// bf16 <-> fp32 helpers (finite values only; RNE rounding)
static __device__ __forceinline__ unsigned short f2bf(float f) {
    unsigned int u = __float_as_uint(f);
    u = (u + 0x7FFF + ((u >> 16) & 1)) >> 16;   // round-to-nearest-even
    return (unsigned short)u;
}
static __device__ __forceinline__ float blo(uint32 w) { return __uint_as_float(w << 16); }
static __device__ __forceinline__ float bhi(uint32 w) { return __uint_as_float(w & 0xFFFF0000u); }

// ---------------------------------------------------------------------------
// K0: convert concat(user,item) fp32 -> bf16 bufC (NT in: read-once stream).
// ---------------------------------------------------------------------------
__global__ void lgcn_convert(const float4* __restrict__ user4,
                             const float4* __restrict__ item4,
                             ushort4* __restrict__ bufC) {
    size_t i = (size_t)blockIdx.x * blockDim.x + threadIdx.x;
    const size_t n4 = N_ELEM / 4, nu4 = (size_t)NUM_USERS * DIM / 4;
    if (i >= n4) return;
    float4 v = (i < nu4) ? ntload(&user4[i]) : ntload(&item4[i - nu4]);
    ushort4 o;
    o.x = f2bf(v.x); o.y = f2bf(v.y); o.z = f2bf(v.z); o.w = f2bf(v.w);
    bufC[i] = o;
}

// ---------------------------------------------------------------------------
// K1: (bucket, group) histogram. g must equal append's g = blockIdx&7 with
// BLK=256 -> g = (e>>8)&7 = (i>>6)&7 for int4 index i.
// ---------------------------------------------------------------------------
__global__ void lgcn_bhist(const int4* __restrict__ rows4, int* __restrict__ bcnt) {
    int i = blockIdx.x * blockDim.x + threadIdx.x;
    if (i >= NNZ / 4) return;
    int g = (i >> 6) & (NSUB - 1);
    int4 r = ntload(&rows4[i]);
    atomicAdd(&bcnt[(((r.x >> BKT_SHIFT) << 3) + g) * PAD], 1);
    atomicAdd(&bcnt[(((r.y >> BKT_SHIFT) << 3) + g) * PAD], 1);
    atomicAdd(&bcnt[(((r.z >> BKT_SHIFT) << 3) + g) * PAD], 1);
    atomicAdd(&bcnt[(((r.w >> BKT_SHIFT) << 3) + g) * PAD], 1);
}

// ---------------------------------------------------------------------------
// K2: segment allocation. One thread per bucket: sums its 8 sub-counts,
// wave-scan + one cursor atomic per wave (order-free), lays sub-segments
// contiguously so bucket span = [bbase[b], bbase[b]+btot[b]).
// ---------------------------------------------------------------------------
__global__ void lgcn_balloc(const int* __restrict__ bcnt, int* __restrict__ bbase,
                            int* __restrict__ btot, int* __restrict__ bfill,
                            int* __restrict__ cursor) {
    int b = blockIdx.x * blockDim.x + threadIdx.x;
    int lane = threadIdx.x & 63;
    int cg[NSUB];
    int tot = 0;
    if (b < NBKT) {
        #pragma unroll
        for (int g = 0; g < NSUB; ++g) {
            cg[g] = bcnt[((b << 3) + g) * PAD];
            tot += cg[g];
        }
    }
    int s = tot;
    #pragma unroll
    for (int o = 1; o < 64; o <<= 1) {
        int t = __shfl_up(s, o);
        if (lane >= o) s += t;
    }
    int wtot = __shfl(s, 63);
    int wbase = 0;
    if (lane == 63) wbase = atomicAdd(cursor, wtot);
    wbase = __shfl(wbase, 63);
    if (b < NBKT) {
        int base = wbase + (s - tot);
        bbase[b] = base;
        btot[b]  = tot;
        int run = base;
        #pragma unroll
        for (int g = 0; g < NSUB; ++g) {
            bfill[((b << 3) + g) * PAD] = run;
            run += cg[g];
        }
    }
}

// ---------------------------------------------------------------------------
// K3: append edges to the (bucket, g) sub-frontier, g = blockIdx&7 (XCD id
// under round-robin dispatch). WRITE_SIZE shows ~5x amplification (157 MB for
// a 32 MB payload): the 8B scattered stores each cost a ~32B downstream
// sector (no temporal merging -- consecutive slots of a cursor are claimed by
// different waves, microseconds apart). NT-load protection proved NEUTRAL
// (round 4). A fix needs LDS-binned burst flushes; parked.
// staging element = { (local_row<<19) | col , val_bits }  (col<2^19, lr<256)
// ---------------------------------------------------------------------------
__global__ void lgcn_append(const int* __restrict__ rows, const int* __restrict__ cols,
                            const float* __restrict__ vals, int* __restrict__ bfill,
                            int2* __restrict__ staging) {
    int e = blockIdx.x * blockDim.x + threadIdx.x;
    if (e >= NNZ) return;
    int g = blockIdx.x & (NSUB - 1);
    int r   = __builtin_nontemporal_load(&rows[e]);
    int cl  = __builtin_nontemporal_load(&cols[e]);
    float v = __builtin_nontemporal_load(&vals[e]);
    int b = r >> BKT_SHIFT;
    int p = atomicAdd(&bfill[((b << 3) + g) * PAD], 1);
    staging[p] = make_int2(((r & (BKT_ROWS - 1)) << 19) | cl, __float_as_int(v));
}

// ---------------------------------------------------------------------------
// K4: per-bucket LDS sort (256 local rows). Count, block-scan, emit
// desc[row], then re-read the (L2-hot) bucket span and write row-sorted sc.
// ---------------------------------------------------------------------------
__global__ __launch_bounds__(256) void lgcn_bsort(
    const int2* __restrict__ staging, const int* __restrict__ bbase,
    const int* __restrict__ btot, int2* __restrict__ desc, int2* __restrict__ sc)
{
    __shared__ int cnt[BKT_ROWS], pfx[BKT_ROWS], fill[BKT_ROWS];
    int b   = blockIdx.x;
    int tid = threadIdx.x;
    cnt[tid] = 0;
    __syncthreads();
    int base = bbase[b];
    int n    = btot[b];

    // Phase A: count local rows (also warms the span for phase C)
    for (int i = tid; i < n; i += 256)
        atomicAdd(&cnt[staging[base + i].x >> 19], 1);
    __syncthreads();

    // Phase B: block-wide inclusive scan of 256 counts
    int c = cnt[tid];
    pfx[tid] = c;
    __syncthreads();
    for (int o = 1; o < 256; o <<= 1) {
        int t = (tid >= o) ? pfx[tid - o] : 0;
        __syncthreads();
        pfx[tid] += t;
        __syncthreads();
    }
    int excl = pfx[tid] - c;
    fill[tid] = excl;                       // relative to base
    int row = (b << BKT_SHIFT) + tid;
    if (row < N_NODES) desc[row] = make_int2(base + excl, c);
    __syncthreads();

    // Phase C: scatter into row-sorted order within the exclusive bucket span
    for (int i = tid; i < n; i += 256) {
        int2 e = staging[base + i];
        int lr = e.x >> 19;
        int p = atomicAdd(&fill[lr], 1);
        sc[base + p] = make_int2(e.x & 0x7FFFF, e.y);
    }
}

// ---------------------------------------------------------------------------
// Wide group-per-row CSR SpMM. Round-4's 16-lane/dwordx2 version measured
// ~162us/layer, gather-throughput bound (VALUBusy ~2%, FETCH small -> L2/L3
// served; cost = requests in flight). Now: one row per 8-lane group, 8 rows
// per wave, lane gl owns dims 8gl..8gl+7 (one uint4 = 8 bf16). One gather
// instruction covers 8 edges = 1 KB (vs 4 edges / 512 B) -> per-edge gather
// instruction count halves, bytes-in-flight per wave doubles (4-deep unroll
// = 4 KB). Still NO cross-lane reduction; stores are 1 KB contiguous per
// wave. Pad slots (c=0,v=0) read the hot row-0 line and add 0.
// MODE 1: nxt = bf16x8(acc)            uint4 store    (layers 1,2)
// MODE 2: out = 0.25*(own+e1+e2+acc)   2x float4      (layer 3)
// ---------------------------------------------------------------------------
template<int MODE>
__global__ __launch_bounds__(256) void lgcn_spmm_csr(
    const int2* __restrict__ desc, const int2* __restrict__ sc,
    const uint4* __restrict__ cur4, uint4* __restrict__ nxt4,
    const float4* __restrict__ user4, const float4* __restrict__ item4,
    const uint4* __restrict__ e1b4, const uint4* __restrict__ e2b4,
    float4* __restrict__ out4)
{
    int lane = threadIdx.x & 63;
    int grp  = lane >> 3;              // 8 row-groups per wave
    int gl   = lane & 7;               // lane within group: dims 8gl..8gl+7
    int gb   = grp << 3;
    int row  = blockIdx.x * 32 + (threadIdx.x >> 6) * 8 + grp;  // exact: 9375*32=300000
    int2 d = desc[row];
    int b = d.x, n = d.y;

    // wave-uniform trip count (n is uniform within each 8-lane group)
    int nmax = n;
    nmax = max(nmax, __shfl_xor(nmax, 8));
    nmax = max(nmax, __shfl_xor(nmax, 16));
    nmax = max(nmax, __shfl_xor(nmax, 32));

    float a0lo = 0.f, a0hi = 0.f, a1lo = 0.f, a1hi = 0.f;
    float a2lo = 0.f, a2hi = 0.f, a3lo = 0.f, a3hi = 0.f;

    for (int k0 = 0; k0 < nmax; k0 += 8) {
        int m = n - k0;                      // may be <=0 for finished groups
        int c = 0, vbits = 0;
        if (gl < m) {
            int2 cv = ntload(&sc[b + k0 + gl]);
            c = cv.x; vbits = cv.y;
        }
        int mp = min(max(m, 0), 8);
        mp = max(mp, __shfl_xor(mp, 8));
        mp = max(mp, __shfl_xor(mp, 16));
        mp = max(mp, __shfl_xor(mp, 32));
        mp = (mp + 3) & ~3;
        for (int j = 0; j < mp; j += 4) {
            int   i0 = __shfl(c, gb + j);
            int   i1 = __shfl(c, gb + j + 1);
            int   i2 = __shfl(c, gb + j + 2);
            int   i3 = __shfl(c, gb + j + 3);
            float v0 = __int_as_float(__shfl(vbits, gb + j));
            float v1 = __int_as_float(__shfl(vbits, gb + j + 1));
            float v2 = __int_as_float(__shfl(vbits, gb + j + 2));
            float v3 = __int_as_float(__shfl(vbits, gb + j + 3));
            uint4 x0 = cur4[(size_t)i0 * 8 + gl];
            uint4 x1 = cur4[(size_t)i1 * 8 + gl];
            uint4 x2 = cur4[(size_t)i2 * 8 + gl];
            uint4 x3 = cur4[(size_t)i3 * 8 + gl];
            a0lo += v0 * blo(x0.x); a0hi += v0 * bhi(x0.x);
            a1lo += v0 * blo(x0.y); a1hi += v0 * bhi(x0.y);
            a2lo += v0 * blo(x0.z); a2hi += v0 * bhi(x0.z);
            a3lo += v0 * blo(x0.w); a3hi += v0 * bhi(x0.w);
            a0lo += v1 * blo(x1.x); a0hi += v1 * bhi(x1.x);
            a1lo += v1 * blo(x1.y); a1hi += v1 * bhi(x1.y);
            a2lo += v1 * blo(x1.z); a2hi += v1 * bhi(x1.z);
            a3lo += v1 * blo(x1.w); a3hi += v1 * bhi(x1.w);
            a0lo += v2 * blo(x2.x); a0hi += v2 * bhi(x2.x);
            a1lo += v2 * blo(x2.y); a1hi += v2 * bhi(x2.y);
            a2lo += v2 * blo(x2.z); a2hi += v2 * bhi(x2.z);
            a3lo += v2 * blo(x2.w); a3hi += v2 * bhi(x2.w);
            a0lo += v3 * blo(x3.x); a0hi += v3 * bhi(x3.x);
            a1lo += v3 * blo(x3.y); a1hi += v3 * bhi(x3.y);
            a2lo += v3 * blo(x3.z); a2hi += v3 * bhi(x3.z);
            a3lo += v3 * blo(x3.w); a3hi += v3 * bhi(x3.w);
        }
    }

    if constexpr (MODE == 1) {
        uint4 o;
        o.x = ((uint32)f2bf(a0hi) << 16) | (uint32)f2bf(a0lo);
        o.y = ((uint32)f2bf(a1hi) << 16) | (uint32)f2bf(a1lo);
        o.z = ((uint32)f2bf(a2hi) << 16) | (uint32)f2bf(a2lo);
        o.w = ((uint32)f2bf(a3hi) << 16) | (uint32)f2bf(a3lo);
        nxt4[(size_t)row * 8 + gl] = o;      // 1KB contiguous per wave
    } else {
        const float4* ownp = (row < NUM_USERS)
            ? &user4[(size_t)row * 16 + 2 * gl]
            : &item4[(size_t)(row - NUM_USERS) * 16 + 2 * gl];
        float4 w0 = ntload(ownp);
        float4 w1 = ntload(ownp + 1);
        uint4 e1 = ntload(&e1b4[(size_t)row * 8 + gl]);
        uint4 e2 = ntload(&e2b4[(size_t)row * 8 + gl]);
        float4 o0, o1;
        o0.x = 0.25f * (w0.x + blo(e1.x) + blo(e2.x) + a0lo);
        o0.y = 0.25f * (w0.y + bhi(e1.x) + bhi(e2.x) + a0hi);
        o0.z = 0.25f * (w0.z + blo(e1.y) + blo(e2.y) + a1lo);
        o0.w = 0.25f * (w0.w + bhi(e1.y) + bhi(e2.y) + a1hi);
        o1.x = 0.25f * (w1.x + blo(e1.z) + blo(e2.z) + a2lo);
        o1.y = 0.25f * (w1.y + bhi(e1.z) + bhi(e2.z) + a2hi);
        o1.z = 0.25f * (w1.z + blo(e1.w) + blo(e2.w) + a3lo);
        o1.w = 0.25f * (w1.w + bhi(e1.w) + bhi(e2.w) + a3hi);
        out4[(size_t)row * 16 + 2 * gl]     = o0;
        out4[(size_t)row * 16 + 2 * gl + 1] = o1;
    }
}

extern "C" void kernel_launch(void* const* d_in, const int* in_sizes, int n_in,
                              void* d_out, int out_size, void* d_ws, size_t ws_size,
                              hipStream_t stream) {
    const float* user_emb = (const float*)d_in[0];
    const float* item_emb = (const float*)d_in[1];
    const float* vals     = (const float*)d_in[2];
    const int*   rows     = (const int*)d_in[3];
    const int*   cols     = (const int*)d_in[4];
    float* out = (float*)d_out;

    // ---- workspace carve-up (~185 MB) ----
    char* ws = (char*)d_ws;
    size_t off = 0;
    unsigned short* bufC = (unsigned short*)(ws + off); off += N_ELEM * 2;      // 38.4 MB
    unsigned short* buf0 = (unsigned short*)(ws + off); off += N_ELEM * 2;      // 38.4 MB
    unsigned short* buf1 = (unsigned short*)(ws + off); off += N_ELEM * 2;      // 38.4 MB
    int2* staging = (int2*)(ws + off); off += (size_t)NNZ * 8;                  // 32 MB
    int2* sc      = (int2*)(ws + off); off += (size_t)NNZ * 8;                  // 32 MB
    int2* desc    = (int2*)(ws + off); off += (size_t)N_NODES * 8;              // 2.4 MB
    int*  bcnt    = (int*) (ws + off); off += (size_t)NBKT * NSUB * PAD * 4;    // 1.2 MB
    int*  cursor  = (int*) (ws + off); off += 256;                              // w/ bcnt memset
    int*  bbase   = (int*) (ws + off); off += (size_t)NBKT * 4;
    int*  btot    = (int*) (ws + off); off += (size_t)NBKT * 4;
    int*  bfill   = (int*) (ws + off); off += (size_t)NBKT * NSUB * PAD * 4;    // 1.2 MB

    const int BLK = 256;
    dim3 grid_conv((unsigned)((N_ELEM / 4 + BLK - 1) / BLK));   // 18750
    dim3 grid_edge((NNZ + BLK - 1) / BLK);                      // 15625
    dim3 grid_edge4((NNZ / 4 + BLK - 1) / BLK);                 // 3907
    dim3 grid_bkt((NBKT + BLK - 1) / BLK);                      // 5
    dim3 grid_sort(NBKT);                                       // 1172
    dim3 grid_spmm(N_NODES / 32);                               // 9375

    // ---- build (once per call; ws re-poisoned before every launch) ----
    (void)hipMemsetAsync(bcnt, 0, (size_t)NBKT * NSUB * PAD * 4 + 256, stream); // bcnt+cursor
    lgcn_convert<<<grid_conv, BLK, 0, stream>>>(
        (const float4*)user_emb, (const float4*)item_emb, (ushort4*)bufC);
    lgcn_bhist<<<grid_edge4, BLK, 0, stream>>>((const int4*)rows, bcnt);
    lgcn_balloc<<<grid_bkt, BLK, 0, stream>>>(bcnt, bbase, btot, bfill, cursor);
    lgcn_append<<<grid_edge, BLK, 0, stream>>>(rows, cols, vals, bfill, staging);
    lgcn_bsort<<<grid_sort, BLK, 0, stream>>>(staging, bbase, btot, desc, sc);

    // ---- 3 propagation layers ----
    lgcn_spmm_csr<1><<<grid_spmm, BLK, 0, stream>>>(
        desc, sc, (const uint4*)bufC, (uint4*)buf0,
        nullptr, nullptr, nullptr, nullptr, nullptr);
    lgcn_spmm_csr<1><<<grid_spmm, BLK, 0, stream>>>(
        desc, sc, (const uint4*)buf0, (uint4*)buf1,
        nullptr, nullptr, nullptr, nullptr, nullptr);
    lgcn_spmm_csr<2><<<grid_spmm, BLK, 0, stream>>>(
        desc, sc, (const uint4*)buf1, nullptr,
        (const float4*)user_emb, (const float4*)item_emb,
        (const uint4*)buf0, (const uint4*)buf1, (float4*)out);
}